// Round 1
// baseline (1697.580 us; speedup 1.0000x reference)
//
#include <hip/hip_runtime.h>
#include <cstdio>

constexpr int TS = 16; // padded row stride (floats) => 64B-aligned rows, 1 line per gather

// ---------------- CSR build ----------------

__global__ __launch_bounds__(256) void k_init(int* cnt_r, int* cnt_c, int n) {
  int i = blockIdx.x * 256 + threadIdx.x;
  if (i < n) { cnt_r[i] = 1; cnt_c[i] = 1; }  // +1 = self loop
}

__global__ __launch_bounds__(256) void k_count(const int* __restrict__ row, const int* __restrict__ col,
                                               int* cnt_r, int* cnt_c, int E) {
  int e = blockIdx.x * 256 + threadIdx.x;
  if (e < E) {
    atomicAdd(&cnt_r[row[e]], 1);
    atomicAdd(&cnt_c[col[e]], 1);
  }
}

__global__ __launch_bounds__(256) void k_dinv(const int* __restrict__ cnt_r, const int* __restrict__ cnt_c,
                                              float* dinv_r, float* dinv_c, int n) {
  int i = blockIdx.x * 256 + threadIdx.x;
  if (i < n) {
    dinv_r[i] = rsqrtf((float)cnt_r[i]);
    dinv_c[i] = rsqrtf((float)cnt_c[i]);
  }
}

// exclusive prefix scan over n ints: 3 kernels (CHUNK=2048 per block)
__global__ __launch_bounds__(256) void k_scanA(const int* __restrict__ in, int* __restrict__ out,
                                               int* __restrict__ bsum, int n) {
  int base = blockIdx.x * 2048 + threadIdx.x * 8;
  int v[8];
  int run = 0;
#pragma unroll
  for (int i = 0; i < 8; ++i) { int idx = base + i; v[i] = (idx < n) ? in[idx] : 0; }
#pragma unroll
  for (int i = 0; i < 8; ++i) { int t = v[i]; v[i] = run; run += t; }
  __shared__ int s[256];
  s[threadIdx.x] = run;
  __syncthreads();
  for (int off = 1; off < 256; off <<= 1) {
    int t = (threadIdx.x >= off) ? s[threadIdx.x - off] : 0;
    __syncthreads();
    s[threadIdx.x] += t;
    __syncthreads();
  }
  int toff = s[threadIdx.x] - run;  // exclusive offset for this thread within block
#pragma unroll
  for (int i = 0; i < 8; ++i) { int idx = base + i; if (idx < n) out[idx] = v[i] + toff; }
  if (threadIdx.x == 255) bsum[blockIdx.x] = s[255];
}

__global__ __launch_bounds__(256) void k_scanB(int* bsum, int nb) {
  __shared__ int s[256];
  int t = threadIdx.x;
  int v = (t < nb) ? bsum[t] : 0;
  s[t] = v;
  __syncthreads();
  for (int off = 1; off < 256; off <<= 1) {
    int tv = (t >= off) ? s[t - off] : 0;
    __syncthreads();
    s[t] += tv;
    __syncthreads();
  }
  if (t < nb) bsum[t] = s[t] - v;  // exclusive
}

__global__ __launch_bounds__(256) void k_scanC(int* __restrict__ out, const int* __restrict__ bsum,
                                               int n, int total) {
  int base = blockIdx.x * 2048 + threadIdx.x * 8;
  int add = bsum[blockIdx.x];
#pragma unroll
  for (int i = 0; i < 8; ++i) { int idx = base + i; if (idx < n) out[idx] += add; }
  if (blockIdx.x == 0 && threadIdx.x == 0) out[n] = total;
}

__global__ __launch_bounds__(256) void k_self(const int* __restrict__ rp_r, const int* __restrict__ rp_c,
                                              int* cur_r, int* cur_c, int* csr_r, int* csr_c, int n) {
  int v = blockIdx.x * 256 + threadIdx.x;
  if (v < n) {
    int sr = rp_r[v] + atomicAdd(&cur_r[v], 1);
    csr_r[sr] = v;
    int sc = rp_c[v] + atomicAdd(&cur_c[v], 1);
    csr_c[sc] = v;
  }
}

__global__ __launch_bounds__(256) void k_scatter(const int* __restrict__ row, const int* __restrict__ col,
                                                 const int* __restrict__ rp_r, const int* __restrict__ rp_c,
                                                 int* cur_r, int* cur_c, int* csr_r, int* csr_c, int E) {
  int e = blockIdx.x * 256 + threadIdx.x;
  if (e < E) {
    int r = row[e], c = col[e];
    int sr = rp_r[r] + atomicAdd(&cur_r[r], 1);
    csr_r[sr] = c;  // row-CSR stores source = col
    int sc = rp_c[c] + atomicAdd(&cur_c[c], 1);
    csr_c[sc] = r;  // col-CSR stores source = row
  }
}

// ---------------- x @ W1 : [N,128] x [128,10] -> t (stride 16) ----------------
// 16 lanes per row; each lane owns an 8-wide j-chunk of W1 in registers (grid-strided).
__global__ __launch_bounds__(256) void k_xw(const float* __restrict__ x, const float* __restrict__ W1,
                                            float* __restrict__ t, int n) {
  int tid = blockIdx.x * 256 + threadIdx.x;
  int sub = tid & 15;
  int rowStart = tid >> 4;
  int rowStride = (gridDim.x * 256) >> 4;
  float w[8][10];
#pragma unroll
  for (int jj = 0; jj < 8; ++jj)
#pragma unroll
    for (int k = 0; k < 10; ++k) w[jj][k] = W1[(sub * 8 + jj) * 10 + k];
  for (int row = rowStart; row < n; row += rowStride) {
    const float* xr = x + (size_t)row * 128 + sub * 8;
    float4 a = *(const float4*)xr;
    float4 b = *(const float4*)(xr + 4);
    float xv[8] = {a.x, a.y, a.z, a.w, b.x, b.y, b.z, b.w};
    float acc[10];
#pragma unroll
    for (int k = 0; k < 10; ++k) acc[k] = 0.f;
#pragma unroll
    for (int jj = 0; jj < 8; ++jj)
#pragma unroll
      for (int k = 0; k < 10; ++k) acc[k] = fmaf(xv[jj], w[jj][k], acc[k]);
#pragma unroll
    for (int off = 1; off < 16; off <<= 1)
#pragma unroll
      for (int k = 0; k < 10; ++k) acc[k] += __shfl_xor(acc[k], off);
    if (sub == 0) {
      float* o = t + (size_t)row * TS;
      *(float4*)o = make_float4(acc[0], acc[1], acc[2], acc[3]);
      *(float4*)(o + 4) = make_float4(acc[4], acc[5], acc[6], acc[7]);
      *(float2*)(o + 8) = make_float2(acc[8], acc[9]);
    }
  }
}

// ---------------- fused GCN layer: out = relu( (dinv_d * sum_src dinv_s*h[src]) @ W + b ) -------
// quarter-wave (16 lanes) per destination; self-loop is a CSR entry.
template <bool USE_W>
__global__ __launch_bounds__(256) void k_agg10(const float* __restrict__ tin, float* __restrict__ tout,
                                               const int* __restrict__ csr, const int* __restrict__ rowptr,
                                               const float* __restrict__ dinv, const float* __restrict__ W,
                                               const float* __restrict__ bias, int n) {
  int tid = blockIdx.x * 256 + threadIdx.x;
  int q = tid >> 4, lane = tid & 15;
  if (q >= n) return;
  int beg = rowptr[q], end = rowptr[q + 1];
  float acc[10];
#pragma unroll
  for (int k = 0; k < 10; ++k) acc[k] = 0.f;
  for (int p = beg + lane; p < end; p += 16) {
    int src = csr[p];
    float ds = dinv[src];
    const float* r = tin + (size_t)src * TS;
    float4 a = *(const float4*)r;
    float4 b = *(const float4*)(r + 4);
    float2 c = *(const float2*)(r + 8);
    float hv[10] = {a.x, a.y, a.z, a.w, b.x, b.y, b.z, b.w, c.x, c.y};
#pragma unroll
    for (int k = 0; k < 10; ++k) acc[k] = fmaf(ds, hv[k], acc[k]);
  }
#pragma unroll
  for (int off = 1; off < 16; off <<= 1)
#pragma unroll
    for (int k = 0; k < 10; ++k) acc[k] += __shfl_xor(acc[k], off);
  if (lane < 10) {
    float dd = dinv[q];
    float o = bias[lane];
    if (USE_W) {
#pragma unroll
      for (int m = 0; m < 10; ++m) o = fmaf(acc[m] * dd, W[m * 10 + lane], o);
    } else {
#pragma unroll
      for (int m = 0; m < 10; ++m)
        if (m == lane) o += acc[m] * dd;
    }
    o = fmaxf(o, 0.f);
    tout[(size_t)q * TS + lane] = o;
  }
}

// ---------------- output layer: probs[q] = dinv_d * sum dinv_s*t5[src] + bo ----------------
__global__ __launch_bounds__(256) void k_agg1(const float* __restrict__ t5, float* __restrict__ probs,
                                              const int* __restrict__ csr, const int* __restrict__ rowptr,
                                              const float* __restrict__ dinv, const float* __restrict__ bo,
                                              int n) {
  int tid = blockIdx.x * 256 + threadIdx.x;
  int q = tid >> 4, lane = tid & 15;
  if (q >= n) return;
  int beg = rowptr[q], end = rowptr[q + 1];
  float acc = 0.f;
  for (int p = beg + lane; p < end; p += 16) {
    int src = csr[p];
    acc = fmaf(dinv[src], t5[src], acc);
  }
#pragma unroll
  for (int off = 1; off < 16; off <<= 1) acc += __shfl_xor(acc, off);
  if (lane == 0) probs[q] = fmaf(dinv[q], acc, bo[0]);
}

// ---------------- t5 = h4 @ Wo, plus column-sum partials for the mean ----------------
__global__ __launch_bounds__(256) void k_t5mean(const float* __restrict__ h, const float* __restrict__ Wo,
                                                float* __restrict__ t5, float* __restrict__ part, int n) {
  int tid = blockIdx.x * 256 + threadIdx.x;
  float wo[10];
#pragma unroll
  for (int k = 0; k < 10; ++k) wo[k] = Wo[k];
  float p[10];
#pragma unroll
  for (int k = 0; k < 10; ++k) p[k] = 0.f;
  for (int rowi = tid; rowi < n; rowi += 128 * 256) {
    const float* r = h + (size_t)rowi * TS;
    float4 a = *(const float4*)r;
    float4 b = *(const float4*)(r + 4);
    float2 c = *(const float2*)(r + 8);
    float hv[10] = {a.x, a.y, a.z, a.w, b.x, b.y, b.z, b.w, c.x, c.y};
    float s = 0.f;
#pragma unroll
    for (int k = 0; k < 10; ++k) { s = fmaf(hv[k], wo[k], s); p[k] += hv[k]; }
    t5[rowi] = s;
  }
#pragma unroll
  for (int off = 1; off < 64; off <<= 1)
#pragma unroll
    for (int k = 0; k < 10; ++k) p[k] += __shfl_xor(p[k], off);
  __shared__ float sp[4][10];
  int w = threadIdx.x >> 6, ln = threadIdx.x & 63;
  if (ln == 0) {
#pragma unroll
    for (int k = 0; k < 10; ++k) sp[w][k] = p[k];
  }
  __syncthreads();
  if (threadIdx.x < 10)
    part[blockIdx.x * 10 + threadIdx.x] =
        sp[0][threadIdx.x] + sp[1][threadIdx.x] + sp[2][threadIdx.x] + sp[3][threadIdx.x];
}

__global__ void k_finish(const float* __restrict__ part, const float* __restrict__ Wdn,
                         const float* __restrict__ bdn, const float* __restrict__ Wv,
                         const float* __restrict__ bv, float* __restrict__ out, int n, int nPart) {
  __shared__ float m[10];
  int t = threadIdx.x;
  if (t < 10) {
    float s = 0.f;
    for (int b = 0; b < nPart; ++b) s += part[b * 10 + t];
    m[t] = s / (float)n;
  }
  __syncthreads();
  if (t == 0) {
    float pn = bdn[0], vv = bv[0];
    for (int k = 0; k < 10; ++k) {
      pn = fmaf(m[k], Wdn[k], pn);
      vv = fmaf(m[k], Wv[k], vv);
    }
    out[n] = pn;
    out[n + 1] = vv;
  }
}

extern "C" void kernel_launch(void* const* d_in, const int* in_sizes, int n_in,
                              void* d_out, int out_size, void* d_ws, size_t ws_size,
                              hipStream_t stream) {
  const float* x  = (const float*)d_in[0];
  const int* ei   = (const int*)d_in[1];
  const float* W1 = (const float*)d_in[2];
  const float* b1 = (const float*)d_in[3];
  const float* W2 = (const float*)d_in[4];
  const float* b2 = (const float*)d_in[5];
  const float* Wp = (const float*)d_in[6];
  const float* bp = (const float*)d_in[7];
  const float* W3 = (const float*)d_in[8];
  const float* b3 = (const float*)d_in[9];
  const float* Wo = (const float*)d_in[10];
  const float* bo = (const float*)d_in[11];
  const float* Wdn = (const float*)d_in[12];
  const float* bdn = (const float*)d_in[13];
  const float* Wv = (const float*)d_in[14];
  const float* bv = (const float*)d_in[15];

  int N = in_sizes[0] / 128;
  int E = in_sizes[1] / 2;
  const int* row = ei;
  const int* colv = ei + E;
  float* out = (float*)d_out;

  char* ws = (char*)d_ws;
  size_t off = 0;
  auto alloc = [&](size_t b) -> void* {
    void* p = ws + off;
    off += (b + 255) & ~(size_t)255;
    return p;
  };
  float* t_a = (float*)alloc((size_t)N * TS * 4);
  float* t_b = (float*)alloc((size_t)N * TS * 4);
  int* csr_r = (int*)alloc((size_t)(E + N) * 4);
  int* csr_c = (int*)alloc((size_t)(E + N) * 4);
  int* cnt_r = (int*)alloc((size_t)N * 4);
  int* cnt_c = (int*)alloc((size_t)N * 4);
  float* dinv_r = (float*)alloc((size_t)N * 4);
  float* dinv_c = (float*)alloc((size_t)N * 4);
  int* rp_r = (int*)alloc((size_t)(N + 1) * 4);
  int* rp_c = (int*)alloc((size_t)(N + 1) * 4);
  int* cur_r = (int*)alloc((size_t)N * 4);
  int* cur_c = (int*)alloc((size_t)N * 4);
  int* bsum = (int*)alloc(1024);
  float* t5 = (float*)alloc((size_t)N * 4);
  float* part = (float*)alloc(128 * 10 * 4);
  if (off > ws_size) {
    fprintf(stderr, "WS too small: need %zu have %zu\n", off, ws_size);
    return;
  }

  int nb = (N + 255) / 256;
  int eb = (E + 255) / 256;
  int sb = (N + 2047) / 2048;
  int ab = (int)(((size_t)N * 16 + 255) / 256);

  k_init<<<nb, 256, 0, stream>>>(cnt_r, cnt_c, N);
  k_count<<<eb, 256, 0, stream>>>(row, colv, cnt_r, cnt_c, E);
  k_dinv<<<nb, 256, 0, stream>>>(cnt_r, cnt_c, dinv_r, dinv_c, N);
  k_scanA<<<sb, 256, 0, stream>>>(cnt_r, rp_r, bsum, N);
  k_scanB<<<1, 256, 0, stream>>>(bsum, sb);
  k_scanC<<<sb, 256, 0, stream>>>(rp_r, bsum, N, E + N);
  k_scanA<<<sb, 256, 0, stream>>>(cnt_c, rp_c, bsum, N);
  k_scanB<<<1, 256, 0, stream>>>(bsum, sb);
  k_scanC<<<sb, 256, 0, stream>>>(rp_c, bsum, N, E + N);
  hipMemsetAsync(cur_r, 0, (size_t)N * 4, stream);
  hipMemsetAsync(cur_c, 0, (size_t)N * 4, stream);
  k_self<<<nb, 256, 0, stream>>>(rp_r, rp_c, cur_r, cur_c, csr_r, csr_c, N);
  k_scatter<<<eb, 256, 0, stream>>>(row, colv, rp_r, rp_c, cur_r, cur_c, csr_r, csr_c, E);
  k_xw<<<2048, 256, 0, stream>>>(x, W1, t_a, N);
  k_agg10<false><<<ab, 256, 0, stream>>>(t_a, t_b, csr_r, rp_r, dinv_r, nullptr, b1, N);
  k_agg10<true><<<ab, 256, 0, stream>>>(t_b, t_a, csr_r, rp_r, dinv_r, W2, b2, N);
  k_agg10<true><<<ab, 256, 0, stream>>>(t_a, t_b, csr_c, rp_c, dinv_c, Wp, bp, N);
  k_agg10<true><<<ab, 256, 0, stream>>>(t_b, t_a, csr_r, rp_r, dinv_r, W3, b3, N);
  k_t5mean<<<128, 256, 0, stream>>>(t_a, Wo, t5, part, N);
  k_agg1<<<ab, 256, 0, stream>>>(t5, out, csr_r, rp_r, dinv_r, bo, N);
  k_finish<<<1, 64, 0, stream>>>(part, Wdn, bdn, Wv, bv, out, N, 128);
}

// Round 2
// 875.013 us; speedup vs baseline: 1.9401x; 1.9401x over previous
//
#include <hip/hip_runtime.h>
#include <cstdio>

constexpr int TS = 16;       // padded row stride (floats) => 64B rows, 1 line per gather
constexpr int NPB = 256;     // nodes per bucket (power of 2)
constexpr int BSH = 8;       // log2(NPB)
constexpr int BIN_CHUNK = 16384;  // edges per block in k_bin

// ---------------- bucketed CSR build (no per-edge device atomics) ----------------

// Pass A: bucket histogram. Per-block LDS hist, then ~nbuck global atomics per block.
__global__ __launch_bounds__(256) void k_hist(const int* __restrict__ dst, int* __restrict__ bcnt,
                                              int E, int nbuck) {
  __shared__ int h[1024];
  int t = threadIdx.x;
  for (int i = t; i < 1024; i += 256) h[i] = 0;
  __syncthreads();
  int stride = gridDim.x * 256;
  for (int e = blockIdx.x * 256 + t; e < E; e += stride)
    atomicAdd(&h[dst[e] >> BSH], 1);
  __syncthreads();
  for (int b = t; b < nbuck; b += 256)
    if (h[b]) atomicAdd(&bcnt[b], h[b]);
}

// scan bucket counts -> bucket bases + global cursors (one block)
__global__ __launch_bounds__(1024) void k_bscan(const int* __restrict__ bcnt, int* __restrict__ base,
                                                int* __restrict__ gcur, int nbuck, int E) {
  __shared__ int s[1024];
  int t = threadIdx.x;
  int v = (t < nbuck) ? bcnt[t] : 0;
  s[t] = v;
  __syncthreads();
  for (int off = 1; off < 1024; off <<= 1) {
    int x = (t >= off) ? s[t - off] : 0;
    __syncthreads();
    s[t] += x;
    __syncthreads();
  }
  if (t < nbuck) { int ex = s[t] - v; base[t] = ex; gcur[t] = ex; }
  if (t == 0) base[nbuck] = E;
}

// Pass B: bin edges by dst bucket as packed words (local_dst<<18 | src).
// One chunk-reservation atomic per (block,bucket); per-edge cursors live in LDS.
__global__ __launch_bounds__(256) void k_bin(const int* __restrict__ dst, const int* __restrict__ src,
                                             int* __restrict__ gcur, int* __restrict__ bin, int E) {
  __shared__ int h[1024];
  int t = threadIdx.x;
  for (int i = t; i < 1024; i += 256) h[i] = 0;
  __syncthreads();
  int e0 = blockIdx.x * BIN_CHUNK + t;
  int eend = min(E, (blockIdx.x + 1) * BIN_CHUNK);
  for (int e = e0; e < eend; e += 256) atomicAdd(&h[dst[e] >> BSH], 1);
  __syncthreads();
  for (int b = t; b < 1024; b += 256) {
    int c = h[b];
    h[b] = c ? atomicAdd(&gcur[b], c) : 0;
  }
  __syncthreads();
  for (int e = e0; e < eend; e += 256) {
    int d = dst[e];
    int slot = atomicAdd(&h[d >> BSH], 1);
    bin[slot] = ((d & (NPB - 1)) << 18) | src[e];
  }
}

// Pass C: one WG per bucket builds rowptr/dinv/csr segment with LDS-only atomics.
// Self-loop counted (+1) and emitted first. csr window is L2-resident (~33KB).
__global__ __launch_bounds__(256) void k_buildcsr(const int* __restrict__ bin, const int* __restrict__ base,
                                                  int* __restrict__ rowptr, int* __restrict__ csr,
                                                  float* __restrict__ dinv, int N, int Etot) {
  __shared__ int cnt[256];
  __shared__ int sc[256];
  int t = threadIdx.x;
  int b = blockIdx.x;
  int node0 = b << BSH;
  int nn = min(NPB, N - node0);
  cnt[t] = (t < nn) ? 1 : 0;  // self loop
  __syncthreads();
  int ebeg = base[b], eend = base[b + 1];
  for (int p = ebeg + t; p < eend; p += 256) atomicAdd(&cnt[bin[p] >> 18], 1);
  __syncthreads();
  int v = cnt[t];
  sc[t] = v;
  __syncthreads();
  for (int off = 1; off < 256; off <<= 1) {
    int x = (t >= off) ? sc[t - off] : 0;
    __syncthreads();
    sc[t] += x;
    __syncthreads();
  }
  int excl = sc[t] - v;
  int cbase = ebeg + node0;  // preceding buckets are full => node0 self-loops precede
  if (t < nn) {
    rowptr[node0 + t] = cbase + excl;
    dinv[node0 + t] = rsqrtf((float)v);
    csr[cbase + excl] = node0 + t;  // self loop entry
  }
  __syncthreads();
  cnt[t] = excl + 1;  // cursor past self loop
  __syncthreads();
  for (int p = ebeg + t; p < eend; p += 256) {
    int w = bin[p];
    int slot = atomicAdd(&cnt[w >> 18], 1);
    csr[cbase + slot] = w & 0x3FFFF;
  }
  if (b == 0 && t == 0) rowptr[N] = Etot + N;
}

// ---------------- x @ W1 : [N,128] x [128,10] -> t (stride 16) ----------------
__global__ __launch_bounds__(256) void k_xw(const float* __restrict__ x, const float* __restrict__ W1,
                                            float* __restrict__ t, int n) {
  int tid = blockIdx.x * 256 + threadIdx.x;
  int sub = tid & 15;
  int rowStart = tid >> 4;
  int rowStride = (gridDim.x * 256) >> 4;
  float w[8][10];
#pragma unroll
  for (int jj = 0; jj < 8; ++jj)
#pragma unroll
    for (int k = 0; k < 10; ++k) w[jj][k] = W1[(sub * 8 + jj) * 10 + k];
  for (int row = rowStart; row < n; row += rowStride) {
    const float* xr = x + (size_t)row * 128 + sub * 8;
    float4 a = *(const float4*)xr;
    float4 b = *(const float4*)(xr + 4);
    float xv[8] = {a.x, a.y, a.z, a.w, b.x, b.y, b.z, b.w};
    float acc[10];
#pragma unroll
    for (int k = 0; k < 10; ++k) acc[k] = 0.f;
#pragma unroll
    for (int jj = 0; jj < 8; ++jj)
#pragma unroll
      for (int k = 0; k < 10; ++k) acc[k] = fmaf(xv[jj], w[jj][k], acc[k]);
#pragma unroll
    for (int off = 1; off < 16; off <<= 1)
#pragma unroll
      for (int k = 0; k < 10; ++k) acc[k] += __shfl_xor(acc[k], off);
    if (sub == 0) {
      float* o = t + (size_t)row * TS;
      *(float4*)o = make_float4(acc[0], acc[1], acc[2], acc[3]);
      *(float4*)(o + 4) = make_float4(acc[4], acc[5], acc[6], acc[7]);
      *(float2*)(o + 8) = make_float2(acc[8], acc[9]);
    }
  }
}

// ---------------- fused GCN layer ----------------
template <bool USE_W>
__global__ __launch_bounds__(256) void k_agg10(const float* __restrict__ tin, float* __restrict__ tout,
                                               const int* __restrict__ csr, const int* __restrict__ rowptr,
                                               const float* __restrict__ dinv, const float* __restrict__ W,
                                               const float* __restrict__ bias, int n) {
  int tid = blockIdx.x * 256 + threadIdx.x;
  int q = tid >> 4, lane = tid & 15;
  if (q >= n) return;
  int beg = rowptr[q], end = rowptr[q + 1];
  float acc[10];
#pragma unroll
  for (int k = 0; k < 10; ++k) acc[k] = 0.f;
  for (int p = beg + lane; p < end; p += 16) {
    int src = csr[p];
    float ds = dinv[src];
    const float* r = tin + (size_t)src * TS;
    float4 a = *(const float4*)r;
    float4 b = *(const float4*)(r + 4);
    float2 c = *(const float2*)(r + 8);
    float hv[10] = {a.x, a.y, a.z, a.w, b.x, b.y, b.z, b.w, c.x, c.y};
#pragma unroll
    for (int k = 0; k < 10; ++k) acc[k] = fmaf(ds, hv[k], acc[k]);
  }
#pragma unroll
  for (int off = 1; off < 16; off <<= 1)
#pragma unroll
    for (int k = 0; k < 10; ++k) acc[k] += __shfl_xor(acc[k], off);
  if (lane < 10) {
    float dd = dinv[q];
    float o = bias[lane];
    if (USE_W) {
#pragma unroll
      for (int m = 0; m < 10; ++m) o = fmaf(acc[m] * dd, W[m * 10 + lane], o);
    } else {
#pragma unroll
      for (int m = 0; m < 10; ++m)
        if (m == lane) o += acc[m] * dd;
    }
    o = fmaxf(o, 0.f);
    tout[(size_t)q * TS + lane] = o;
  }
}

// ---------------- output layer ----------------
__global__ __launch_bounds__(256) void k_agg1(const float* __restrict__ t5, float* __restrict__ probs,
                                              const int* __restrict__ csr, const int* __restrict__ rowptr,
                                              const float* __restrict__ dinv, const float* __restrict__ bo,
                                              int n) {
  int tid = blockIdx.x * 256 + threadIdx.x;
  int q = tid >> 4, lane = tid & 15;
  if (q >= n) return;
  int beg = rowptr[q], end = rowptr[q + 1];
  float acc = 0.f;
  for (int p = beg + lane; p < end; p += 16) {
    int src = csr[p];
    acc = fmaf(dinv[src], t5[src], acc);
  }
#pragma unroll
  for (int off = 1; off < 16; off <<= 1) acc += __shfl_xor(acc, off);
  if (lane == 0) probs[q] = fmaf(dinv[q], acc, bo[0]);
}

// ---------------- t5 = h4 @ Wo, plus column-sum partials for the mean ----------------
__global__ __launch_bounds__(256) void k_t5mean(const float* __restrict__ h, const float* __restrict__ Wo,
                                                float* __restrict__ t5, float* __restrict__ part, int n) {
  int tid = blockIdx.x * 256 + threadIdx.x;
  float wo[10];
#pragma unroll
  for (int k = 0; k < 10; ++k) wo[k] = Wo[k];
  float p[10];
#pragma unroll
  for (int k = 0; k < 10; ++k) p[k] = 0.f;
  for (int rowi = tid; rowi < n; rowi += 128 * 256) {
    const float* r = h + (size_t)rowi * TS;
    float4 a = *(const float4*)r;
    float4 b = *(const float4*)(r + 4);
    float2 c = *(const float2*)(r + 8);
    float hv[10] = {a.x, a.y, a.z, a.w, b.x, b.y, b.z, b.w, c.x, c.y};
    float s = 0.f;
#pragma unroll
    for (int k = 0; k < 10; ++k) { s = fmaf(hv[k], wo[k], s); p[k] += hv[k]; }
    t5[rowi] = s;
  }
#pragma unroll
  for (int off = 1; off < 64; off <<= 1)
#pragma unroll
    for (int k = 0; k < 10; ++k) p[k] += __shfl_xor(p[k], off);
  __shared__ float sp[4][10];
  int w = threadIdx.x >> 6, ln = threadIdx.x & 63;
  if (ln == 0) {
#pragma unroll
    for (int k = 0; k < 10; ++k) sp[w][k] = p[k];
  }
  __syncthreads();
  if (threadIdx.x < 10)
    part[blockIdx.x * 10 + threadIdx.x] =
        sp[0][threadIdx.x] + sp[1][threadIdx.x] + sp[2][threadIdx.x] + sp[3][threadIdx.x];
}

__global__ void k_finish(const float* __restrict__ part, const float* __restrict__ Wdn,
                         const float* __restrict__ bdn, const float* __restrict__ Wv,
                         const float* __restrict__ bv, float* __restrict__ out, int n, int nPart) {
  __shared__ float m[10];
  int t = threadIdx.x;
  if (t < 10) {
    float s = 0.f;
    for (int b = 0; b < nPart; ++b) s += part[b * 10 + t];
    m[t] = s / (float)n;
  }
  __syncthreads();
  if (t == 0) {
    float pn = bdn[0], vv = bv[0];
    for (int k = 0; k < 10; ++k) {
      pn = fmaf(m[k], Wdn[k], pn);
      vv = fmaf(m[k], Wv[k], vv);
    }
    out[n] = pn;
    out[n + 1] = vv;
  }
}

extern "C" void kernel_launch(void* const* d_in, const int* in_sizes, int n_in,
                              void* d_out, int out_size, void* d_ws, size_t ws_size,
                              hipStream_t stream) {
  const float* x  = (const float*)d_in[0];
  const int* ei   = (const int*)d_in[1];
  const float* W1 = (const float*)d_in[2];
  const float* b1 = (const float*)d_in[3];
  const float* W2 = (const float*)d_in[4];
  const float* b2 = (const float*)d_in[5];
  const float* Wp = (const float*)d_in[6];
  const float* bp = (const float*)d_in[7];
  const float* W3 = (const float*)d_in[8];
  const float* b3 = (const float*)d_in[9];
  const float* Wo = (const float*)d_in[10];
  const float* bo = (const float*)d_in[11];
  const float* Wdn = (const float*)d_in[12];
  const float* bdn = (const float*)d_in[13];
  const float* Wv = (const float*)d_in[14];
  const float* bv = (const float*)d_in[15];

  int N = in_sizes[0] / 128;
  int E = in_sizes[1] / 2;
  const int* row = ei;
  const int* colv = ei + E;
  float* out = (float*)d_out;
  int nbuck = (N + NPB - 1) >> BSH;

  char* ws = (char*)d_ws;
  size_t off = 0;
  auto alloc = [&](size_t b) -> void* {
    void* p = ws + off;
    off += (b + 255) & ~(size_t)255;
    return p;
  };
  int* csr_r = (int*)alloc((size_t)(E + N) * 4);
  int* csr_c = (int*)alloc((size_t)(E + N) * 4);
  int* rp_r = (int*)alloc((size_t)(N + 1) * 4);
  int* rp_c = (int*)alloc((size_t)(N + 1) * 4);
  float* dinv_r = (float*)alloc((size_t)N * 4);
  float* dinv_c = (float*)alloc((size_t)N * 4);
  int* bcnt = (int*)alloc(4096);
  int* bbase = (int*)alloc(4100);
  int* gcur = (int*)alloc(4096);
  // union region: bin (build phase) overlaps t_a/t_b/t5/part (compute phase)
  size_t binB = (size_t)E * 4;
  size_t tB = (size_t)N * TS * 4 * 2 + (size_t)N * 4 + 128 * 10 * 4 + 1024;
  char* region = (char*)alloc(binB > tB ? binB : tB);
  int* bin = (int*)region;
  float* t_a = (float*)region;
  float* t_b = (float*)(region + (size_t)N * TS * 4);
  float* t5 = (float*)(region + (size_t)N * TS * 4 * 2);
  float* part = (float*)(region + (size_t)N * TS * 4 * 2 + (size_t)N * 4);
  if (off > ws_size) {
    fprintf(stderr, "WS too small: need %zu have %zu\n", off, ws_size);
    return;
  }

  int bb = (E + BIN_CHUNK - 1) / BIN_CHUNK;
  int ab = (int)(((size_t)N * 16 + 255) / 256);

  // build row-CSR (dst=row, src=col)
  hipMemsetAsync(bcnt, 0, (size_t)nbuck * 4, stream);
  k_hist<<<512, 256, 0, stream>>>(row, bcnt, E, nbuck);
  k_bscan<<<1, 1024, 0, stream>>>(bcnt, bbase, gcur, nbuck, E);
  k_bin<<<bb, 256, 0, stream>>>(row, colv, gcur, bin, E);
  k_buildcsr<<<nbuck, 256, 0, stream>>>(bin, bbase, rp_r, csr_r, dinv_r, N, E);
  // build col-CSR (dst=col, src=row)
  hipMemsetAsync(bcnt, 0, (size_t)nbuck * 4, stream);
  k_hist<<<512, 256, 0, stream>>>(colv, bcnt, E, nbuck);
  k_bscan<<<1, 1024, 0, stream>>>(bcnt, bbase, gcur, nbuck, E);
  k_bin<<<bb, 256, 0, stream>>>(colv, row, gcur, bin, E);
  k_buildcsr<<<nbuck, 256, 0, stream>>>(bin, bbase, rp_c, csr_c, dinv_c, N, E);

  // network
  k_xw<<<2048, 256, 0, stream>>>(x, W1, t_a, N);
  k_agg10<false><<<ab, 256, 0, stream>>>(t_a, t_b, csr_r, rp_r, dinv_r, nullptr, b1, N);
  k_agg10<true><<<ab, 256, 0, stream>>>(t_b, t_a, csr_r, rp_r, dinv_r, W2, b2, N);
  k_agg10<true><<<ab, 256, 0, stream>>>(t_a, t_b, csr_c, rp_c, dinv_c, Wp, bp, N);
  k_agg10<true><<<ab, 256, 0, stream>>>(t_b, t_a, csr_r, rp_r, dinv_r, W3, b3, N);
  k_t5mean<<<128, 256, 0, stream>>>(t_a, Wo, t5, part, N);
  k_agg1<<<ab, 256, 0, stream>>>(t5, out, csr_r, rp_r, dinv_r, bo, N);
  k_finish<<<1, 64, 0, stream>>>(part, Wdn, bdn, Wv, bv, out, N, 128);
}